// Round 2
// baseline (398.045 us; speedup 1.0000x reference)
//
#include <hip/hip_runtime.h>
#include <hip/hip_bf16.h>
#include <stdint.h>

typedef __bf16 bf16x8 __attribute__((ext_vector_type(8)));
typedef float  f32x4  __attribute__((ext_vector_type(4)));
typedef unsigned short u16;
typedef unsigned int   u32;

#define B_  32
#define N_  128
#define F_  128
#define G_  300
#define GP  320   // G padded to multiple of 32

__device__ __forceinline__ float b2f(u16 v){
  union { u32 u; float f; } x; x.u = ((u32)v) << 16; return x.f;
}
__device__ __forceinline__ u16 f2b(float f){
  union { float f; u32 u; } x; x.f = f;
  u32 r = x.u + 0x7FFFu + ((x.u >> 16) & 1u);
  return (u16)(r >> 16);
}
// shifted softplus: log(0.5*exp(x)+0.5) = max(x,0) + log(0.5 + 0.5*exp(-|x|))
__device__ __forceinline__ float sspf(float x){
  return fmaxf(x, 0.0f) + __logf(0.5f + 0.5f*__expf(-fabsf(x)));
}
__device__ __forceinline__ f32x4 mfma16(bf16x8 a, bf16x8 b, f32x4 c){
  return __builtin_amdgcn_mfma_f32_16x16x32_bf16(a, b, c, 0, 0, 0);
}

// ---------------- setup: transpose+cast weight matrices to bf16 ----------------
__global__ __launch_bounds__(256) void k_setup(const float* __restrict__ w_f1,
                                               const float* __restrict__ w_f2,
                                               const float* __restrict__ w_in2f,
                                               u16* __restrict__ w1t,
                                               u16* __restrict__ w2t,
                                               u16* __restrict__ wi2t){
  int idx = blockIdx.x*256 + threadIdx.x;
  if (idx < 128*GP){
    int k = idx / GP, g = idx % GP;
    w1t[idx] = (g < G_) ? f2b(w_f1[g*F_ + k]) : (u16)0;
  } else if (idx < 128*GP + 128*128){
    int j = idx - 128*GP; int h = j / 128, k = j % 128;
    w2t[h*128 + k] = f2b(w_f2[k*128 + h]);
  } else if (idx < 128*GP + 2*128*128){
    int j = idx - 128*GP - 128*128; int h = j / 128, ff = j % 128;
    wi2t[h*128 + ff] = f2b(w_in2f[ff*128 + h]);
  }
}

// ---------------- x = emb[z] (fp32) ----------------
__global__ __launch_bounds__(256) void k_embed(const int* __restrict__ z,
                                               const float* __restrict__ emb,
                                               float* __restrict__ x){
  int idx = blockIdx.x*256 + threadIdx.x;   // < 32*128*128
  int bn = idx >> 7, ff = idx & 127;
  x[idx] = emb[z[bn]*F_ + ff];
}

// ---------------- filter network: W[b,i,j,h] (bf16), one block per (b,i) ----------------
__global__ __launch_bounds__(256, 2) void k_filter(const float* __restrict__ r,
                                                   const u16* __restrict__ w1t,
                                                   const u16* __restrict__ w2t,
                                                   const float* __restrict__ b_f1,
                                                   const float* __restrict__ b_f2,
                                                   u16* __restrict__ W,
                                                   int b0){
  __shared__ __attribute__((aligned(16))) u16 bw1[128][40];   // w1t chunk [k][32g], padded
  __shared__ __attribute__((aligned(16))) u16 w1s[128][136];  // W1 [j][k]
  __shared__ __attribute__((aligned(16))) u16 w2s[128][136];  // w2t [h][k]
  __shared__ float dsh[128];
  __shared__ float bs1[128], bs2[128];

  int bl  = blockIdx.x >> 7, i = blockIdx.x & 127;
  int b   = b0 + bl;
  int tid = threadIdx.x, lane = tid & 63, wave = tid >> 6;
  int m   = lane & 15,  q   = lane >> 4;

  if (tid < 128){ bs1[tid] = b_f1[tid]; bs2[tid] = b_f2[tid]; }
  if (tid < 128){
    const float* rb = r + (size_t)(b*N_)*3;
    float dx = rb[i*3]   - rb[tid*3];
    float dy = rb[i*3+1] - rb[tid*3+1];
    float dz = rb[i*3+2] - rb[tid*3+2];
    dsh[tid] = sqrtf(dx*dx + dy*dy + dz*dz + 1e-12f);
  }
  { // stage w2t -> w2s
    int row = tid >> 1, half = (tid & 1)*64;
    const u16* src = w2t + row*128 + half;
    u16* dst = &w2s[row][half];
    #pragma unroll
    for (int v = 0; v < 8; ++v)
      *reinterpret_cast<bf16x8*>(dst + v*8) = *reinterpret_cast<const bf16x8*>(src + v*8);
  }
  __syncthreads();

  int jr = (wave >> 1)*64, kc = (wave & 1)*64;
  const float cst = 30.0f/299.0f;
  float dmy[4];
  #pragma unroll
  for (int mi = 0; mi < 4; ++mi) dmy[mi] = dsh[jr + mi*16 + m];

  f32x4 acc[4][4];
  #pragma unroll
  for (int mi = 0; mi < 4; ++mi)
    #pragma unroll
    for (int ni = 0; ni < 4; ++ni) acc[mi][ni] = (f32x4){0.f,0.f,0.f,0.f};

  // ---- GEMM1: W1 = rbf @ w_f1, K = 320 ----
  for (int ks = 0; ks < 10; ++ks){
    int g0 = ks*32;
    { // stage w1t chunk
      int row = tid >> 1, half = (tid & 1)*16;
      const u16* src = w1t + row*GP + g0 + half;
      *reinterpret_cast<bf16x8*>(&bw1[row][half])     = *reinterpret_cast<const bf16x8*>(src);
      *reinterpret_cast<bf16x8*>(&bw1[row][half + 8]) = *reinterpret_cast<const bf16x8*>(src + 8);
    }
    __syncthreads();
    bf16x8 afr[4];
    #pragma unroll
    for (int mi = 0; mi < 4; ++mi){
      float dj = dmy[mi];
      #pragma unroll
      for (int t = 0; t < 8; ++t){
        float td = dj - cst*(float)(g0 + q*8 + t);
        afr[mi][t] = (__bf16)__expf(-10.0f*td*td);
      }
    }
    bf16x8 bfr[4];
    #pragma unroll
    for (int ni = 0; ni < 4; ++ni)
      bfr[ni] = *reinterpret_cast<const bf16x8*>(&bw1[kc + ni*16 + m][q*8]);
    #pragma unroll
    for (int mi = 0; mi < 4; ++mi)
      #pragma unroll
      for (int ni = 0; ni < 4; ++ni)
        acc[mi][ni] = mfma16(afr[mi], bfr[ni], acc[mi][ni]);
    __syncthreads();
  }

  // ---- epilogue 1: + b_f1, ssp, to LDS as bf16 ----
  #pragma unroll
  for (int mi = 0; mi < 4; ++mi)
    #pragma unroll
    for (int ni = 0; ni < 4; ++ni)
      #pragma unroll
      for (int rr = 0; rr < 4; ++rr){
        int row = jr + mi*16 + q*4 + rr;
        int col = kc + ni*16 + m;
        w1s[row][col] = f2b(sspf(acc[mi][ni][rr] + bs1[col]));
      }
  __syncthreads();

  // ---- GEMM2: W = W1 @ w_f2, K = 128 ----
  #pragma unroll
  for (int mi = 0; mi < 4; ++mi)
    #pragma unroll
    for (int ni = 0; ni < 4; ++ni) acc[mi][ni] = (f32x4){0.f,0.f,0.f,0.f};
  #pragma unroll
  for (int ks = 0; ks < 4; ++ks){
    int k0 = ks*32;
    bf16x8 af[4], bf[4];
    #pragma unroll
    for (int mi = 0; mi < 4; ++mi)
      af[mi] = *reinterpret_cast<const bf16x8*>(&w1s[jr + mi*16 + m][k0 + q*8]);
    #pragma unroll
    for (int ni = 0; ni < 4; ++ni)
      bf[ni] = *reinterpret_cast<const bf16x8*>(&w2s[kc + ni*16 + m][k0 + q*8]);
    #pragma unroll
    for (int mi = 0; mi < 4; ++mi)
      #pragma unroll
      for (int ni = 0; ni < 4; ++ni)
        acc[mi][ni] = mfma16(af[mi], bf[ni], acc[mi][ni]);
  }
  u16* Wp = W + ((size_t)(bl*N_ + i))*N_*F_;
  #pragma unroll
  for (int mi = 0; mi < 4; ++mi)
    #pragma unroll
    for (int ni = 0; ni < 4; ++ni)
      #pragma unroll
      for (int rr = 0; rr < 4; ++rr){
        int row = jr + mi*16 + q*4 + rr;
        int col = kc + ni*16 + m;
        Wp[row*F_ + col] = f2b(acc[mi][ni][rr] + bs2[col]);
      }
}

// ---------------- f = x @ w_in2f (fp32 out), one block per b ----------------
__global__ __launch_bounds__(256) void k_inlin(const float* __restrict__ x,
                                               const u16* __restrict__ wi2t,
                                               float* __restrict__ f,
                                               int b0){
  __shared__ __attribute__((aligned(16))) u16 xa[128][136];
  __shared__ __attribute__((aligned(16))) u16 wb[128][136];
  int b = b0 + blockIdx.x;
  int tid = threadIdx.x, lane = tid & 63, wave = tid >> 6;
  int m = lane & 15, q = lane >> 4;
  {
    int row = tid >> 1, half = (tid & 1)*64;
    const float* src = x + ((size_t)b*N_ + row)*F_ + half;
    #pragma unroll
    for (int v = 0; v < 16; ++v){
      float4 t = *reinterpret_cast<const float4*>(src + v*4);
      xa[row][half + v*4]     = f2b(t.x);
      xa[row][half + v*4 + 1] = f2b(t.y);
      xa[row][half + v*4 + 2] = f2b(t.z);
      xa[row][half + v*4 + 3] = f2b(t.w);
    }
    const u16* s2 = wi2t + row*128 + half;
    #pragma unroll
    for (int v = 0; v < 8; ++v)
      *reinterpret_cast<bf16x8*>(&wb[row][half + v*8]) = *reinterpret_cast<const bf16x8*>(s2 + v*8);
  }
  __syncthreads();
  int jr = (wave >> 1)*64, kc = (wave & 1)*64;
  f32x4 acc[4][4];
  #pragma unroll
  for (int mi = 0; mi < 4; ++mi)
    #pragma unroll
    for (int ni = 0; ni < 4; ++ni) acc[mi][ni] = (f32x4){0.f,0.f,0.f,0.f};
  #pragma unroll
  for (int ks = 0; ks < 4; ++ks){
    int k0 = ks*32;
    bf16x8 af[4], bf[4];
    #pragma unroll
    for (int mi = 0; mi < 4; ++mi)
      af[mi] = *reinterpret_cast<const bf16x8*>(&xa[jr + mi*16 + m][k0 + q*8]);
    #pragma unroll
    for (int ni = 0; ni < 4; ++ni)
      bf[ni] = *reinterpret_cast<const bf16x8*>(&wb[kc + ni*16 + m][k0 + q*8]);
    #pragma unroll
    for (int mi = 0; mi < 4; ++mi)
      #pragma unroll
      for (int ni = 0; ni < 4; ++ni)
        acc[mi][ni] = mfma16(af[mi], bf[ni], acc[mi][ni]);
  }
  float* fp = f + (size_t)b*N_*F_;
  #pragma unroll
  for (int mi = 0; mi < 4; ++mi)
    #pragma unroll
    for (int ni = 0; ni < 4; ++ni)
      #pragma unroll
      for (int rr = 0; rr < 4; ++rr)
        fp[(jr + mi*16 + q*4 + rr)*F_ + kc + ni*16 + m] = acc[mi][ni][rr];
}

// ---------------- cfconv + atom-wise MLP + residual; block = (b, 16-row i-tile) ----------------
__global__ __launch_bounds__(256) void k_interact(const float* __restrict__ f,
                                                  const u16* __restrict__ W,
                                                  const float* __restrict__ w_f2out,
                                                  const float* __restrict__ b_f2out,
                                                  const float* __restrict__ w_out,
                                                  const float* __restrict__ b_out,
                                                  float* __restrict__ x,
                                                  int b0){
  __shared__ __attribute__((aligned(16))) float fsh[128][132];
  __shared__ float ysh[16][132];
  int bl = blockIdx.x >> 3, i0 = (blockIdx.x & 7)*16;
  int b  = b0 + bl;
  int tid = threadIdx.x;
  int il = tid >> 4, hq = tid & 15, h0 = hq*8;
  {
    int row = tid >> 1, half = (tid & 1)*64;
    const float* src = f + ((size_t)b*N_ + row)*F_ + half;
    #pragma unroll
    for (int v = 0; v < 16; ++v)
      *reinterpret_cast<float4*>(&fsh[row][half + v*4]) = *reinterpret_cast<const float4*>(src + v*4);
  }
  __syncthreads();

  // cfconv: y[i,h] = sum_j W[b,i,j,h] * f[b,j,h]
  float y[8] = {0,0,0,0,0,0,0,0};
  const u16* Wrow = W + (((size_t)bl*N_ + i0 + il)*N_)*F_ + h0;
  for (int j = 0; j < 128; ++j){
    bf16x8 wv = *reinterpret_cast<const bf16x8*>(Wrow + (size_t)j*F_);
    float4 fa = *reinterpret_cast<const float4*>(&fsh[j][h0]);
    float4 fb = *reinterpret_cast<const float4*>(&fsh[j][h0 + 4]);
    y[0] += (float)wv[0]*fa.x; y[1] += (float)wv[1]*fa.y;
    y[2] += (float)wv[2]*fa.z; y[3] += (float)wv[3]*fa.w;
    y[4] += (float)wv[4]*fb.x; y[5] += (float)wv[5]*fb.y;
    y[6] += (float)wv[6]*fb.z; y[7] += (float)wv[7]*fb.w;
  }
  #pragma unroll
  for (int t = 0; t < 8; ++t) ysh[il][h0 + t] = y[t];
  __syncthreads();

  // y2 = ssp(y @ w_f2out + b_f2out)   (fp32 weights, exact)
  float y2[8] = {0,0,0,0,0,0,0,0};
  for (int k = 0; k < 128; ++k){
    float yv = ysh[il][k];
    float4 wa = *reinterpret_cast<const float4*>(w_f2out + k*F_ + h0);
    float4 wb = *reinterpret_cast<const float4*>(w_f2out + k*F_ + h0 + 4);
    y2[0] += yv*wa.x; y2[1] += yv*wa.y; y2[2] += yv*wa.z; y2[3] += yv*wa.w;
    y2[4] += yv*wb.x; y2[5] += yv*wb.y; y2[6] += yv*wb.z; y2[7] += yv*wb.w;
  }
  #pragma unroll
  for (int t = 0; t < 8; ++t) y2[t] = sspf(y2[t] + b_f2out[h0 + t]);
  __syncthreads();
  #pragma unroll
  for (int t = 0; t < 8; ++t) ysh[il][h0 + t] = y2[t];
  __syncthreads();

  // v = y2 @ w_out + b_out ; x += v
  float v2[8] = {0,0,0,0,0,0,0,0};
  for (int k = 0; k < 128; ++k){
    float yv = ysh[il][k];
    float4 wa = *reinterpret_cast<const float4*>(w_out + k*F_ + h0);
    float4 wb = *reinterpret_cast<const float4*>(w_out + k*F_ + h0 + 4);
    v2[0] += yv*wa.x; v2[1] += yv*wa.y; v2[2] += yv*wa.z; v2[3] += yv*wa.w;
    v2[4] += yv*wb.x; v2[5] += yv*wb.y; v2[6] += yv*wb.z; v2[7] += yv*wb.w;
  }
  float* xp = x + ((size_t)b*N_ + i0 + il)*F_ + h0;
  #pragma unroll
  for (int t = 0; t < 8; ++t) xp[t] = xp[t] + v2[t] + b_out[h0 + t];
}

// ---------------- readout: out = ssp(x@w_aw1+b)@w_aw2 + b2 ----------------
__global__ __launch_bounds__(256) void k_readout(const float* __restrict__ x,
                                                 const float* __restrict__ w_aw1,
                                                 const float* __restrict__ b_aw1,
                                                 const float* __restrict__ w_aw2,
                                                 const float* __restrict__ b_aw2,
                                                 float* __restrict__ out){
  int tid = threadIdx.x, lane = tid & 63, wave = tid >> 6;
  int atom = blockIdx.x*4 + wave;           // < 4096
  const float* xr = x + (size_t)atom*F_;
  float a0 = 0.f, a1 = 0.f;
  int f0 = lane, f1 = lane + 64;
  for (int k = 0; k < 128; ++k){
    float xv = xr[k];
    a0 += xv*w_aw1[k*F_ + f0];
    a1 += xv*w_aw1[k*F_ + f1];
  }
  float h0 = sspf(a0 + b_aw1[f0]);
  float h1 = sspf(a1 + b_aw1[f1]);
  float s = h0*w_aw2[f0] + h1*w_aw2[f1];
  #pragma unroll
  for (int off = 32; off; off >>= 1) s += __shfl_down(s, off, 64);
  if (lane == 0) out[atom] = s + b_aw2[0];
}

extern "C" void kernel_launch(void* const* d_in, const int* in_sizes, int n_in,
                              void* d_out, int out_size, void* d_ws, size_t ws_size,
                              hipStream_t stream){
  const int*   z       = (const int*)d_in[0];
  const float* r       = (const float*)d_in[1];
  const float* emb     = (const float*)d_in[2];
  const float* w_in2f  = (const float*)d_in[3];
  const float* w_f1    = (const float*)d_in[4];
  const float* b_f1    = (const float*)d_in[5];
  const float* w_f2    = (const float*)d_in[6];
  const float* b_f2    = (const float*)d_in[7];
  const float* w_f2out = (const float*)d_in[8];
  const float* b_f2out = (const float*)d_in[9];
  const float* w_out   = (const float*)d_in[10];
  const float* b_out   = (const float*)d_in[11];
  const float* w_aw1   = (const float*)d_in[12];
  const float* b_aw1   = (const float*)d_in[13];
  const float* w_aw2   = (const float*)d_in[14];
  const float* b_aw2   = (const float*)d_in[15];

  // workspace layout: small fixed region first, W (chunked over b) after
  char* ws = (char*)d_ws;
  float* x    = (float*)(ws);                        // 2,097,152 B
  float* f    = (float*)(ws + 2097152);              // 2,097,152 B
  u16*   w1t  = (u16*)(ws + 4194304);                //    81,920 B
  u16*   w2t  = (u16*)(ws + 4276224);                //    32,768 B
  u16*   wi2t = (u16*)(ws + 4308992);                //    32,768 B
  const size_t SMALL_END = 4341760;
  u16*   W    = (u16*)(ws + SMALL_END);
  const size_t WB = (size_t)N_*N_*F_*2;              // 4,194,304 B per batch elem

  int chunk_b = 1;
  if (ws_size > SMALL_END + WB){
    size_t cb = (ws_size - SMALL_END) / WB;
    chunk_b = (cb > 32) ? 32 : (int)cb;
  }

  k_setup<<<288, 256, 0, stream>>>(w_f1, w_f2, w_in2f, w1t, w2t, wi2t);
  k_embed<<<2048, 256, 0, stream>>>(z, emb, x);
  for (int b0 = 0; b0 < B_; b0 += chunk_b){
    int cb = (B_ - b0 < chunk_b) ? (B_ - b0) : chunk_b;
    k_filter<<<cb*128, 256, 0, stream>>>(r, w1t, w2t, b_f1, b_f2, W, b0);
    for (int it = 0; it < 3; ++it){
      k_inlin<<<cb, 256, 0, stream>>>(x, wi2t, f, b0);
      k_interact<<<cb*8, 256, 0, stream>>>(f, W, w_f2out, b_f2out, w_out, b_out, x, b0);
    }
  }
  k_readout<<<1024, 256, 0, stream>>>(x, w_aw1, b_aw1, w_aw2, b_aw2, (float*)d_out);
}

// Round 3
// 337.476 us; speedup vs baseline: 1.1795x; 1.1795x over previous
//
#include <hip/hip_runtime.h>
#include <hip/hip_bf16.h>
#include <stdint.h>

typedef __bf16 bf16x8 __attribute__((ext_vector_type(8)));
typedef float  f32x4  __attribute__((ext_vector_type(4)));
typedef unsigned int u32x4 __attribute__((ext_vector_type(4)));
typedef unsigned short u16;
typedef unsigned int   u32;

#define B_  32
#define N_  128
#define F_  128
#define G_  300
#define GP  320   // G padded to multiple of 32

__device__ __forceinline__ float b2f(u16 v){
  union { u32 u; float f; } x; x.u = ((u32)v) << 16; return x.f;
}
__device__ __forceinline__ u16 f2b(float f){
  union { float f; u32 u; } x; x.f = f;
  u32 r = x.u + 0x7FFFu + ((x.u >> 16) & 1u);
  return (u16)(r >> 16);
}
// shifted softplus: log(0.5*exp(x)+0.5) = max(x,0) + log(0.5 + 0.5*exp(-|x|))
__device__ __forceinline__ float sspf(float x){
  return fmaxf(x, 0.0f) + __logf(0.5f + 0.5f*__expf(-fabsf(x)));
}
__device__ __forceinline__ f32x4 mfma16(bf16x8 a, bf16x8 b, f32x4 c){
  return __builtin_amdgcn_mfma_f32_16x16x32_bf16(a, b, c, 0, 0, 0);
}

// ---------------- setup: transpose+cast weight matrices to bf16 ----------------
__global__ __launch_bounds__(256) void k_setup(const float* __restrict__ w_f1,
                                               const float* __restrict__ w_f2,
                                               const float* __restrict__ w_in2f,
                                               u16* __restrict__ w1t,
                                               u16* __restrict__ w2t,
                                               u16* __restrict__ wi2t){
  int idx = blockIdx.x*256 + threadIdx.x;
  if (idx < 128*GP){
    int k = idx / GP, g = idx % GP;
    w1t[idx] = (g < G_) ? f2b(w_f1[g*F_ + k]) : (u16)0;
  } else if (idx < 128*GP + 128*128){
    int j = idx - 128*GP; int h = j / 128, k = j % 128;
    w2t[h*128 + k] = f2b(w_f2[k*128 + h]);
  } else if (idx < 128*GP + 2*128*128){
    int j = idx - 128*GP - 128*128; int h = j / 128, ff = j % 128;
    wi2t[h*128 + ff] = f2b(w_in2f[ff*128 + h]);
  }
}

// ---------------- x = emb[z] (fp32) ----------------
__global__ __launch_bounds__(256) void k_embed(const int* __restrict__ z,
                                               const float* __restrict__ emb,
                                               float* __restrict__ x){
  int idx = blockIdx.x*256 + threadIdx.x;   // < 32*128*128
  int bn = idx >> 7, ff = idx & 127;
  x[idx] = emb[z[bn]*F_ + ff];
}

// ---------------- filter network, symmetric tiles ----------------
// block = (bl, tile-pair T (ti<=tj), half). Computes 128 pairs (8 i x 16 j) x 128 h.
// Exploits W[b,i,j,:] == W[b,j,i,:] (d symmetric) via mirror store.
__global__ __launch_bounds__(256, 2) void k_filter(const float* __restrict__ r,
                                                   const u16* __restrict__ w1t,
                                                   const u16* __restrict__ w2t,
                                                   const float* __restrict__ b_f1,
                                                   const float* __restrict__ b_f2,
                                                   u16* __restrict__ W,
                                                   int b0){
  __shared__ __attribute__((aligned(16))) u16 bw1[128][32];   // w1t chunk, XOR-4 swizzle
  __shared__ __attribute__((aligned(16))) u16 w1s[128*128];   // W1 [pair][k], XOR-8 swizzle
  __shared__ __attribute__((aligned(16))) u16 w2s[128*128];   // w2t [h][k] then C-out, XOR-8
  __shared__ float dsh[128];
  __shared__ float bs1[128], bs2s[128];

  int tid = threadIdx.x, lane = tid & 63, wave = tid >> 6;
  int m = lane & 15, q = lane >> 4;

  int idx  = blockIdx.x;
  int half = idx & 1;
  int rem  = idx >> 1;
  int Tt   = rem % 36;
  int bl   = rem / 36;
  int b    = b0 + bl;
  int ti = 0;
  { int cnt = 8;
    while (Tt >= cnt){ Tt -= cnt; cnt--; ti++; } }
  int tj = ti + Tt;
  int i0 = ti*16 + half*8, j0 = tj*16;

  if (tid < 128){ bs1[tid] = b_f1[tid]; bs2s[tid] = b_f2[tid]; }
  const float KS = 3.79828256f;              // sqrt(10*log2(e))
  if (tid < 128){
    const float* rb = r + (size_t)(b*N_)*3;
    int ii = i0 + (tid >> 4), jj = j0 + (tid & 15);
    float dx = rb[ii*3]   - rb[jj*3];
    float dy = rb[ii*3+1] - rb[jj*3+1];
    float dz = rb[ii*3+2] - rb[jj*3+2];
    dsh[tid] = KS * sqrtf(dx*dx + dy*dy + dz*dz + 1e-12f);
  }
  { // stage w2t -> w2s (XOR-8)
    int row = tid >> 1, hc = (tid & 1)*8;
    #pragma unroll
    for (int v = 0; v < 8; ++v){
      int g = hc + v, pg = g ^ (row & 7);
      *reinterpret_cast<bf16x8*>(&w2s[row*128 + pg*8]) =
        *reinterpret_cast<const bf16x8*>(w2t + row*128 + g*8);
    }
  }
  __syncthreads();

  int rows0 = wave*32;                       // this wave owns pair-rows [rows0, rows0+32)
  float sdm0 = dsh[rows0 + m];
  float sdm1 = dsh[rows0 + 16 + m];

  const float KC = KS * (30.0f/299.0f);      // KS * center spacing
  float sct[8];
  #pragma unroll
  for (int t = 0; t < 8; ++t) sct[t] = KC * (float)(q*8 + t);

  f32x4 acc[2][8];
  #pragma unroll
  for (int mi = 0; mi < 2; ++mi)
    #pragma unroll
    for (int ni = 0; ni < 8; ++ni) acc[mi][ni] = (f32x4){0.f,0.f,0.f,0.f};

  // ---- GEMM1: W1 = rbf @ w_f1, K = 320, rbf computed in-register (no dup) ----
  for (int ks = 0; ks < 10; ++ks){
    if (ks) __syncthreads();
    { // stage w1t chunk (XOR-4)
      int row = tid >> 1, gb = (tid & 1)*2;
      const u16* src = w1t + row*GP + ks*32 + gb*8;
      int pg0 = gb ^ (row & 3), pg1 = (gb + 1) ^ (row & 3);
      *reinterpret_cast<bf16x8*>(&bw1[row][pg0*8]) = *reinterpret_cast<const bf16x8*>(src);
      *reinterpret_cast<bf16x8*>(&bw1[row][pg1*8]) = *reinterpret_cast<const bf16x8*>(src + 8);
    }
    __syncthreads();
    bf16x8 afr[2];
    #pragma unroll
    for (int mi = 0; mi < 2; ++mi){
      float sd = mi ? sdm1 : sdm0;
      u32x4 au;
      #pragma unroll
      for (int t2 = 0; t2 < 4; ++t2){
        float t0 = sd - sct[t2*2];
        float t1 = sd - sct[t2*2 + 1];
        float e0 = __builtin_amdgcn_exp2f(-(t0*t0));
        float e1 = __builtin_amdgcn_exp2f(-(t1*t1));
        au[t2] = __builtin_amdgcn_perm(__float_as_uint(e1) + 0x8000u,
                                       __float_as_uint(e0) + 0x8000u, 0x07060302u);
      }
      afr[mi] = __builtin_bit_cast(bf16x8, au);
    }
    #pragma unroll
    for (int t = 0; t < 8; ++t) sct[t] += KC*32.0f;
    #pragma unroll
    for (int ni = 0; ni < 8; ++ni){
      bf16x8 bfr = *reinterpret_cast<const bf16x8*>(&bw1[ni*16 + m][(q ^ (m & 3))*8]);
      acc[0][ni] = mfma16(afr[0], bfr, acc[0][ni]);
      acc[1][ni] = mfma16(afr[1], bfr, acc[1][ni]);
    }
  }

  // ---- epilogue 1: + b_f1, ssp -> w1s (bf16, XOR-8) ----
  #pragma unroll
  for (int mi = 0; mi < 2; ++mi)
    #pragma unroll
    for (int ni = 0; ni < 8; ++ni)
      #pragma unroll
      for (int rr = 0; rr < 4; ++rr){
        int row = rows0 + mi*16 + q*4 + rr;
        int col = ni*16 + m;
        int pg  = (col >> 3) ^ (row & 7);
        w1s[row*128 + pg*8 + (col & 7)] = f2b(sspf(acc[mi][ni][rr] + bs1[col]));
      }
  __syncthreads();

  // ---- GEMM2: W = W1 @ w_f2, K = 128 ----
  f32x4 acc2[2][8];
  #pragma unroll
  for (int mi = 0; mi < 2; ++mi)
    #pragma unroll
    for (int ni = 0; ni < 8; ++ni) acc2[mi][ni] = (f32x4){0.f,0.f,0.f,0.f};
  #pragma unroll
  for (int ks = 0; ks < 4; ++ks){
    bf16x8 af[2];
    #pragma unroll
    for (int mi = 0; mi < 2; ++mi){
      int row = rows0 + mi*16 + m;
      int pg = (ks*4 + q) ^ (row & 7);
      af[mi] = *reinterpret_cast<const bf16x8*>(&w1s[row*128 + pg*8]);
    }
    #pragma unroll
    for (int ni = 0; ni < 8; ++ni){
      int row = ni*16 + m;
      int pg = (ks*4 + q) ^ (row & 7);
      bf16x8 bfv = *reinterpret_cast<const bf16x8*>(&w2s[row*128 + pg*8]);
      acc2[0][ni] = mfma16(af[0], bfv, acc2[0][ni]);
      acc2[1][ni] = mfma16(af[1], bfv, acc2[1][ni]);
    }
  }
  __syncthreads();   // all w2s reads done before reuse as C buffer

  // ---- epilogue 2: + b_f2 -> w2s (bf16, XOR-8) ----
  #pragma unroll
  for (int mi = 0; mi < 2; ++mi)
    #pragma unroll
    for (int ni = 0; ni < 8; ++ni)
      #pragma unroll
      for (int rr = 0; rr < 4; ++rr){
        int row = rows0 + mi*16 + q*4 + rr;
        int col = ni*16 + m;
        int pg  = (col >> 3) ^ (row & 7);
        w2s[row*128 + pg*8 + (col & 7)] = f2b(acc2[mi][ni][rr] + bs2s[col]);
      }
  __syncthreads();

  // ---- coalesced store (+ mirror for off-diagonal tile-pairs) ----
  u16* Wb = W + (size_t)bl * ((size_t)N_*N_*F_);
  bool mir = (ti != tj);
  #pragma unroll
  for (int v = 0; v < 8; ++v){
    int o   = v*4096 + tid*16;        // byte offset in 32 KB C tile
    int row = o >> 8;                 // pair index
    int cg  = (o >> 4) & 15;
    int pg  = cg ^ (row & 7);
    bf16x8 val = *reinterpret_cast<const bf16x8*>(&w2s[row*128 + pg*8]);
    int il = row >> 4, jl = row & 15;
    int cu = (o & 255) >> 1;          // u16 col offset
    *reinterpret_cast<bf16x8*>(Wb + ((size_t)((i0+il)*N_ + (j0+jl)))*F_ + cu) = val;
    if (mir)
      *reinterpret_cast<bf16x8*>(Wb + ((size_t)((j0+jl)*N_ + (i0+il)))*F_ + cu) = val;
  }
}

// ---------------- f = x @ w_in2f (fp32 out), one block per b ----------------
__global__ __launch_bounds__(256) void k_inlin(const float* __restrict__ x,
                                               const u16* __restrict__ wi2t,
                                               float* __restrict__ f,
                                               int b0){
  __shared__ __attribute__((aligned(16))) u16 xa[128][136];
  __shared__ __attribute__((aligned(16))) u16 wb[128][136];
  int b = b0 + blockIdx.x;
  int tid = threadIdx.x, lane = tid & 63, wave = tid >> 6;
  int m = lane & 15, q = lane >> 4;
  {
    int row = tid >> 1, half = (tid & 1)*64;
    const float* src = x + ((size_t)b*N_ + row)*F_ + half;
    #pragma unroll
    for (int v = 0; v < 16; ++v){
      float4 t = *reinterpret_cast<const float4*>(src + v*4);
      xa[row][half + v*4]     = f2b(t.x);
      xa[row][half + v*4 + 1] = f2b(t.y);
      xa[row][half + v*4 + 2] = f2b(t.z);
      xa[row][half + v*4 + 3] = f2b(t.w);
    }
    const u16* s2 = wi2t + row*128 + half;
    #pragma unroll
    for (int v = 0; v < 8; ++v)
      *reinterpret_cast<bf16x8*>(&wb[row][half + v*8]) = *reinterpret_cast<const bf16x8*>(s2 + v*8);
  }
  __syncthreads();
  int jr = (wave >> 1)*64, kc = (wave & 1)*64;
  f32x4 acc[4][4];
  #pragma unroll
  for (int mi = 0; mi < 4; ++mi)
    #pragma unroll
    for (int ni = 0; ni < 4; ++ni) acc[mi][ni] = (f32x4){0.f,0.f,0.f,0.f};
  #pragma unroll
  for (int ks = 0; ks < 4; ++ks){
    int k0 = ks*32;
    bf16x8 af[4], bf[4];
    #pragma unroll
    for (int mi = 0; mi < 4; ++mi)
      af[mi] = *reinterpret_cast<const bf16x8*>(&xa[jr + mi*16 + m][k0 + q*8]);
    #pragma unroll
    for (int ni = 0; ni < 4; ++ni)
      bf[ni] = *reinterpret_cast<const bf16x8*>(&wb[kc + ni*16 + m][k0 + q*8]);
    #pragma unroll
    for (int mi = 0; mi < 4; ++mi)
      #pragma unroll
      for (int ni = 0; ni < 4; ++ni)
        acc[mi][ni] = mfma16(af[mi], bf[ni], acc[mi][ni]);
  }
  float* fp = f + (size_t)b*N_*F_;
  #pragma unroll
  for (int mi = 0; mi < 4; ++mi)
    #pragma unroll
    for (int ni = 0; ni < 4; ++ni)
      #pragma unroll
      for (int rr = 0; rr < 4; ++rr)
        fp[(jr + mi*16 + q*4 + rr)*F_ + kc + ni*16 + m] = acc[mi][ni][rr];
}

// ---------------- cfconv + atom-wise MLP + residual; block = (b, 16-row i-tile) ----------------
__global__ __launch_bounds__(256) void k_interact(const float* __restrict__ f,
                                                  const u16* __restrict__ W,
                                                  const float* __restrict__ w_f2out,
                                                  const float* __restrict__ b_f2out,
                                                  const float* __restrict__ w_out,
                                                  const float* __restrict__ b_out,
                                                  float* __restrict__ x,
                                                  int b0){
  __shared__ __attribute__((aligned(16))) float fsh[128][132];
  __shared__ float ysh[16][132];
  int bl = blockIdx.x >> 3, i0 = (blockIdx.x & 7)*16;
  int b  = b0 + bl;
  int tid = threadIdx.x;
  int il = tid >> 4, hq = tid & 15, h0 = hq*8;
  {
    int row = tid >> 1, half = (tid & 1)*64;
    const float* src = f + ((size_t)b*N_ + row)*F_ + half;
    #pragma unroll
    for (int v = 0; v < 16; ++v)
      *reinterpret_cast<float4*>(&fsh[row][half + v*4]) = *reinterpret_cast<const float4*>(src + v*4);
  }
  __syncthreads();

  // cfconv: y[i,h] = sum_j W[b,i,j,h] * f[b,j,h]
  float y[8] = {0,0,0,0,0,0,0,0};
  const u16* Wrow = W + (((size_t)bl*N_ + i0 + il)*N_)*F_ + h0;
  for (int j = 0; j < 128; ++j){
    bf16x8 wv = *reinterpret_cast<const bf16x8*>(Wrow + (size_t)j*F_);
    float4 fa = *reinterpret_cast<const float4*>(&fsh[j][h0]);
    float4 fb = *reinterpret_cast<const float4*>(&fsh[j][h0 + 4]);
    y[0] += (float)wv[0]*fa.x; y[1] += (float)wv[1]*fa.y;
    y[2] += (float)wv[2]*fa.z; y[3] += (float)wv[3]*fa.w;
    y[4] += (float)wv[4]*fb.x; y[5] += (float)wv[5]*fb.y;
    y[6] += (float)wv[6]*fb.z; y[7] += (float)wv[7]*fb.w;
  }
  #pragma unroll
  for (int t = 0; t < 8; ++t) ysh[il][h0 + t] = y[t];
  __syncthreads();

  // y2 = ssp(y @ w_f2out + b_f2out)   (fp32 weights, exact)
  float y2[8] = {0,0,0,0,0,0,0,0};
  for (int k = 0; k < 128; ++k){
    float yv = ysh[il][k];
    float4 wa = *reinterpret_cast<const float4*>(w_f2out + k*F_ + h0);
    float4 wb = *reinterpret_cast<const float4*>(w_f2out + k*F_ + h0 + 4);
    y2[0] += yv*wa.x; y2[1] += yv*wa.y; y2[2] += yv*wa.z; y2[3] += yv*wa.w;
    y2[4] += yv*wb.x; y2[5] += yv*wb.y; y2[6] += yv*wb.z; y2[7] += yv*wb.w;
  }
  #pragma unroll
  for (int t = 0; t < 8; ++t) y2[t] = sspf(y2[t] + b_f2out[h0 + t]);
  __syncthreads();
  #pragma unroll
  for (int t = 0; t < 8; ++t) ysh[il][h0 + t] = y2[t];
  __syncthreads();

  // v = y2 @ w_out + b_out ; x += v
  float v2[8] = {0,0,0,0,0,0,0,0};
  for (int k = 0; k < 128; ++k){
    float yv = ysh[il][k];
    float4 wa = *reinterpret_cast<const float4*>(w_out + k*F_ + h0);
    float4 wb = *reinterpret_cast<const float4*>(w_out + k*F_ + h0 + 4);
    v2[0] += yv*wa.x; v2[1] += yv*wa.y; v2[2] += yv*wa.z; v2[3] += yv*wa.w;
    v2[4] += yv*wb.x; v2[5] += yv*wb.y; v2[6] += yv*wb.z; v2[7] += yv*wb.w;
  }
  float* xp = x + ((size_t)b*N_ + i0 + il)*F_ + h0;
  #pragma unroll
  for (int t = 0; t < 8; ++t) xp[t] = xp[t] + v2[t] + b_out[h0 + t];
}

// ---------------- readout: out = ssp(x@w_aw1+b)@w_aw2 + b2 ----------------
__global__ __launch_bounds__(256) void k_readout(const float* __restrict__ x,
                                                 const float* __restrict__ w_aw1,
                                                 const float* __restrict__ b_aw1,
                                                 const float* __restrict__ w_aw2,
                                                 const float* __restrict__ b_aw2,
                                                 float* __restrict__ out){
  int tid = threadIdx.x, lane = tid & 63, wave = tid >> 6;
  int atom = blockIdx.x*4 + wave;           // < 4096
  const float* xr = x + (size_t)atom*F_;
  float a0 = 0.f, a1 = 0.f;
  int f0 = lane, f1 = lane + 64;
  for (int k = 0; k < 128; ++k){
    float xv = xr[k];
    a0 += xv*w_aw1[k*F_ + f0];
    a1 += xv*w_aw1[k*F_ + f1];
  }
  float h0 = sspf(a0 + b_aw1[f0]);
  float h1 = sspf(a1 + b_aw1[f1]);
  float s = h0*w_aw2[f0] + h1*w_aw2[f1];
  #pragma unroll
  for (int off = 32; off; off >>= 1) s += __shfl_down(s, off, 64);
  if (lane == 0) out[atom] = s + b_aw2[0];
}

extern "C" void kernel_launch(void* const* d_in, const int* in_sizes, int n_in,
                              void* d_out, int out_size, void* d_ws, size_t ws_size,
                              hipStream_t stream){
  const int*   z       = (const int*)d_in[0];
  const float* r       = (const float*)d_in[1];
  const float* emb     = (const float*)d_in[2];
  const float* w_in2f  = (const float*)d_in[3];
  const float* w_f1    = (const float*)d_in[4];
  const float* b_f1    = (const float*)d_in[5];
  const float* w_f2    = (const float*)d_in[6];
  const float* b_f2    = (const float*)d_in[7];
  const float* w_f2out = (const float*)d_in[8];
  const float* b_f2out = (const float*)d_in[9];
  const float* w_out   = (const float*)d_in[10];
  const float* b_out   = (const float*)d_in[11];
  const float* w_aw1   = (const float*)d_in[12];
  const float* b_aw1   = (const float*)d_in[13];
  const float* w_aw2   = (const float*)d_in[14];
  const float* b_aw2   = (const float*)d_in[15];

  // workspace layout: small fixed region first, W (chunked over b) after
  char* ws = (char*)d_ws;
  float* x    = (float*)(ws);                        // 2,097,152 B
  float* f    = (float*)(ws + 2097152);              // 2,097,152 B
  u16*   w1t  = (u16*)(ws + 4194304);                //    81,920 B
  u16*   w2t  = (u16*)(ws + 4276224);                //    32,768 B
  u16*   wi2t = (u16*)(ws + 4308992);                //    32,768 B
  const size_t SMALL_END = 4341760;
  u16*   W    = (u16*)(ws + SMALL_END);
  const size_t WB = (size_t)N_*N_*F_*2;              // 4,194,304 B per batch elem

  int chunk_b = 1;
  if (ws_size > SMALL_END + WB){
    size_t cb = (ws_size - SMALL_END) / WB;
    chunk_b = (cb > 32) ? 32 : (int)cb;
  }

  k_setup<<<288, 256, 0, stream>>>(w_f1, w_f2, w_in2f, w1t, w2t, wi2t);
  k_embed<<<2048, 256, 0, stream>>>(z, emb, x);
  for (int b0 = 0; b0 < B_; b0 += chunk_b){
    int cb = (B_ - b0 < chunk_b) ? (B_ - b0) : chunk_b;
    k_filter<<<cb*72, 256, 0, stream>>>(r, w1t, w2t, b_f1, b_f2, W, b0);
    for (int it = 0; it < 3; ++it){
      k_inlin<<<cb, 256, 0, stream>>>(x, wi2t, f, b0);
      k_interact<<<cb*8, 256, 0, stream>>>(f, W, w_f2out, b_f2out, w_out, b_out, x, b0);
    }
  }
  k_readout<<<1024, 256, 0, stream>>>(x, w_aw1, b_aw1, w_aw2, b_aw2, (float*)d_out);
}